// Round 1
// baseline (921.381 us; speedup 1.0000x reference)
//
#include <hip/hip_runtime.h>
#include <math.h>

#define H 300
#define BB 64
#define TT 512
#define VV 50257
#define KC 30

// ---------- transpose 300x300: out[r][c] = in[c][r] ----------
__global__ void transpose_k(const float* __restrict__ in, float* __restrict__ out) {
    int idx = blockIdx.x * blockDim.x + threadIdx.x;
    if (idx < H * H) {
        int r = idx / H, c = idx - r * H;
        out[idx] = in[c * H + r];
    }
}

// ---------- ux[t][b][g] = sum_h emb[tok[b][t]][h] * U[g][h] ----------
// one block per t; 256 threads; micro-tile 4 b-rows x 20 g-cols per thread
__global__ __launch_bounds__(256) void ux_k(const int* __restrict__ tokens,
                                            const float* __restrict__ emb,
                                            const float* __restrict__ Ut,   // Ut[h][g] = U[g][h]
                                            float* __restrict__ ux) {
    __shared__ __align__(16) float x_s[KC][BB];     // x_s[k][b]
    __shared__ __align__(16) float ut_s[KC][304];   // ut_s[k][g]
    __shared__ int tok_s[BB];

    const int t = blockIdx.x;
    const int tid = threadIdx.x;
    if (tid < BB) tok_s[tid] = tokens[tid * TT + t];

    const int tb = tid >> 4;          // 0..15
    const int tg = tid & 15;          // 0..15
    const int b0 = tb * 4;
    const int g0 = tg * 20;
    const bool active = (tg < 15);    // 15*20 = 300 cols

    float acc[4][20];
#pragma unroll
    for (int i = 0; i < 4; ++i)
#pragma unroll
        for (int j = 0; j < 20; ++j) acc[i][j] = 0.f;

    __syncthreads();   // tok_s visible

    for (int h0 = 0; h0 < H; h0 += KC) {
        // stage x chunk: 30 h-values for each of 64 tokens
        for (int i = tid; i < BB * 32; i += 256) {
            int b = i >> 5, k = i & 31;
            if (k < KC) x_s[k][b] = emb[tok_s[b] * H + h0 + k];
        }
        // stage Ut chunk rows h0..h0+29
        for (int i = tid; i < KC * H; i += 256) {
            int k = i / H, g = i - k * H;
            ut_s[k][g] = Ut[(h0 + k) * H + g];
        }
        __syncthreads();
        if (active) {
#pragma unroll 2
            for (int k = 0; k < KC; ++k) {
                float4 xa = *reinterpret_cast<const float4*>(&x_s[k][b0]);
                float4 u0 = *reinterpret_cast<const float4*>(&ut_s[k][g0 + 0]);
                float4 u1 = *reinterpret_cast<const float4*>(&ut_s[k][g0 + 4]);
                float4 u2 = *reinterpret_cast<const float4*>(&ut_s[k][g0 + 8]);
                float4 u3 = *reinterpret_cast<const float4*>(&ut_s[k][g0 + 12]);
                float4 u4 = *reinterpret_cast<const float4*>(&ut_s[k][g0 + 16]);
                const float xr[4] = {xa.x, xa.y, xa.z, xa.w};
                const float ur[20] = {u0.x, u0.y, u0.z, u0.w,
                                      u1.x, u1.y, u1.z, u1.w,
                                      u2.x, u2.y, u2.z, u2.w,
                                      u3.x, u3.y, u3.z, u3.w,
                                      u4.x, u4.y, u4.z, u4.w};
#pragma unroll
                for (int i = 0; i < 4; ++i)
#pragma unroll
                    for (int j = 0; j < 20; ++j)
                        acc[i][j] += xr[i] * ur[j];
            }
        }
        __syncthreads();
    }

    if (active) {
#pragma unroll
        for (int i = 0; i < 4; ++i) {
            float* dst = ux + (t * BB + b0 + i) * H + g0;
#pragma unroll
            for (int jq = 0; jq < 5; ++jq) {
                *reinterpret_cast<float4*>(dst + jq * 4) =
                    make_float4(acc[i][jq * 4 + 0], acc[i][jq * 4 + 1],
                                acc[i][jq * 4 + 2], acc[i][jq * 4 + 3]);
            }
        }
    }
}

// ---------- recurrence: one block per batch element, W^T register-resident ----------
// 960 threads: j = tid/300 in {0,1,2} owns h-chunk [j*100, j*100+100), g = tid%300.
__global__ __launch_bounds__(960) void rnn_k(const float* __restrict__ Wt,   // Wt[h][g] = W[g][h]
                                             const float* __restrict__ ux,   // [T][B][H]
                                             const float* __restrict__ ihs,
                                             float* __restrict__ hlast) {
    __shared__ __align__(16) float h_s[304];
    __shared__ float p_s[2 * 304];
    const int b = blockIdx.x;
    const int tid = threadIdx.x;
    const int g = tid % H;
    const int j = tid / H;            // 3 => idle lanes (tid 900..959)

    float w[100];
    if (j < 3) {
#pragma unroll
        for (int i = 0; i < 100; ++i) w[i] = Wt[(j * 100 + i) * H + g];
    }
    if (tid < H) h_s[tid] = ihs[b * H + tid];
    __syncthreads();

    const float* uxb = ux + b * H;
    for (int t = 0; t < TT; ++t) {
        float uv = 0.f;
        if (j == 0) uv = uxb[t * (BB * H) + g];   // independent of h_s: issues early
        float acc = 0.f;
        if (j < 3) {
            const float* hp = &h_s[j * 100];
#pragma unroll
            for (int q = 0; q < 25; ++q) {
                float4 h4 = *reinterpret_cast<const float4*>(hp + q * 4);
                acc += w[q * 4 + 0] * h4.x;
                acc += w[q * 4 + 1] * h4.y;
                acc += w[q * 4 + 2] * h4.z;
                acc += w[q * 4 + 3] * h4.w;
            }
        }
        if (j == 1) p_s[g] = acc;
        if (j == 2) p_s[304 + g] = acc;
        __syncthreads();
        if (j == 0) {
            float z = acc + p_s[g] + p_s[304 + g] + uv;
            h_s[g] = tanhf(z);
        }
        __syncthreads();
    }
    if (tid < H) hlast[b * H + tid] = h_s[tid];
}

// ---------- logits: out[b][v] = h_last[b] . Wout[v] + bout[v] ----------
// 512 threads; lane = b; each wave does 4 wave-uniform v rows (s_load path);
// h_last staged in LDS in two 150-wide passes (static LDS < 64 KB).
__global__ __launch_bounds__(512) void logits_k(const float* __restrict__ hlast,
                                                const float* __restrict__ Wout,
                                                const float* __restrict__ bout,
                                                float* __restrict__ out) {
    __shared__ float hl_s[BB * 151];
    const int tid = threadIdx.x;
    const int lane = tid & 63;                 // = b
    const int wave = __builtin_amdgcn_readfirstlane(tid >> 6);
    const int v0 = blockIdx.x * 32 + wave * 4;

    const int va = min(v0 + 0, VV - 1);
    const int vb = min(v0 + 1, VV - 1);
    const int vc = min(v0 + 2, VV - 1);
    const int vd = min(v0 + 3, VV - 1);
    const float* w0 = Wout + va * H;
    const float* w1 = Wout + vb * H;
    const float* w2 = Wout + vc * H;
    const float* w3 = Wout + vd * H;

    float a0 = 0.f, a1 = 0.f, a2 = 0.f, a3 = 0.f;

    for (int p = 0; p < 2; ++p) {
        for (int i = tid; i < BB * 150; i += 512) {
            int bb = i / 150, h = i - bb * 150;
            hl_s[bb * 151 + h] = hlast[bb * H + p * 150 + h];
        }
        __syncthreads();
        const float* hb = &hl_s[lane * 151];
        const float* w0p = w0 + p * 150;
        const float* w1p = w1 + p * 150;
        const float* w2p = w2 + p * 150;
        const float* w3p = w3 + p * 150;
#pragma unroll 6
        for (int h = 0; h < 150; ++h) {
            float x = hb[h];
            a0 += x * w0p[h];
            a1 += x * w1p[h];
            a2 += x * w2p[h];
            a3 += x * w3p[h];
        }
        __syncthreads();
    }

    long ob = (long)lane * VV;
    if (v0 + 0 < VV) out[ob + v0 + 0] = a0 + bout[v0 + 0];
    if (v0 + 1 < VV) out[ob + v0 + 1] = a1 + bout[v0 + 1];
    if (v0 + 2 < VV) out[ob + v0 + 2] = a2 + bout[v0 + 2];
    if (v0 + 3 < VV) out[ob + v0 + 3] = a3 + bout[v0 + 3];
}

extern "C" void kernel_launch(void* const* d_in, const int* in_sizes, int n_in,
                              void* d_out, int out_size, void* d_ws, size_t ws_size,
                              hipStream_t stream) {
    const float* ihs    = (const float*)d_in[0];
    const int*   tokens = (const int*)  d_in[1];
    const float* emb    = (const float*)d_in[2];
    const float* W      = (const float*)d_in[3];
    const float* U      = (const float*)d_in[4];
    const float* Wout   = (const float*)d_in[5];
    const float* bout   = (const float*)d_in[6];
    float* out = (float*)d_out;

    char* ws = (char*)d_ws;
    float* Wt    = (float*)(ws + 0);          // 360,000 B
    float* Ut    = (float*)(ws + 360000);     // 360,000 B
    float* hlast = (float*)(ws + 720000);     // 76,800 B
    float* ux    = (float*)(ws + 1048576);    // 39,321,600 B  [T][B][H]

    const int tp_blocks = (H * H + 255) / 256;
    transpose_k<<<tp_blocks, 256, 0, stream>>>(W, Wt);
    transpose_k<<<tp_blocks, 256, 0, stream>>>(U, Ut);
    ux_k<<<TT, 256, 0, stream>>>(tokens, emb, Ut, ux);
    rnn_k<<<BB, 960, 0, stream>>>(Wt, ux, ihs, hlast);
    logits_k<<<(VV + 31) / 32, 512, 0, stream>>>(hlast, Wout, bout, out);
}